// Round 4
// baseline (156.943 us; speedup 1.0000x reference)
//
#include <hip/hip_runtime.h>
#include <hip/hip_bf16.h>

#define N_NODES 8192
#define F_IN 256
#define F_OUT 128

typedef __attribute__((ext_vector_type(4))) float f32x4;
typedef __attribute__((ext_vector_type(8))) short bf16x8;

static __device__ __forceinline__ short bfr(float x) {
    __hip_bfloat16 h = __float2bfloat16(x);   // RNE
    union { __hip_bfloat16 h; short s; } u; u.h = h;
    return u.s;
}

static __device__ __forceinline__ void gload16(const void* g, void* l) {
    __builtin_amdgcn_global_load_lds(
        (const __attribute__((address_space(1))) unsigned int*)g,
        (__attribute__((address_space(3))) unsigned int*)l, 16, 0, 0);
}

// Kernel 1: support^T[f][n] = sum_k X[n][k] * W[k][f]   (fp32 accum -> bf16 out)
__global__ __launch_bounds__(256) void support_kernel(
        const float* __restrict__ X, const float* __restrict__ W,
        unsigned short* __restrict__ supT) {
    __shared__ float Xs[32][68];
    __shared__ float Ws[64][128];
    const int t = threadIdx.x;
    const int n0 = blockIdx.x * 32;
    const int tc = t & 31;
    const int tr = t >> 5;
    float acc[4][4];
    #pragma unroll
    for (int i = 0; i < 4; ++i)
        #pragma unroll
        for (int j = 0; j < 4; ++j) acc[i][j] = 0.f;

    for (int k0 = 0; k0 < F_IN; k0 += 64) {
        __syncthreads();
        {
            const int r = t >> 3, kc = (t & 7) * 8;
            const float* src = X + (size_t)(n0 + r) * F_IN + k0 + kc;
            f32x4 v0 = *(const f32x4*)src;
            f32x4 v1 = *(const f32x4*)(src + 4);
            *(f32x4*)&Xs[r][kc]     = v0;
            *(f32x4*)&Xs[r][kc + 4] = v1;
        }
        {
            const int col = t & 127, kb = t >> 7;
            #pragma unroll
            for (int i = 0; i < 32; ++i) {
                const int k = kb + i * 2;
                Ws[k][col] = W[(size_t)(k0 + k) * F_OUT + col];
            }
        }
        __syncthreads();
        #pragma unroll 8
        for (int k = 0; k < 64; ++k) {
            const f32x4 b = *(const f32x4*)&Ws[k][tc * 4];
            float a[4];
            #pragma unroll
            for (int i = 0; i < 4; ++i) a[i] = Xs[tr * 4 + i][k];
            #pragma unroll
            for (int i = 0; i < 4; ++i) {
                acc[i][0] += a[i] * b.x; acc[i][1] += a[i] * b.y;
                acc[i][2] += a[i] * b.z; acc[i][3] += a[i] * b.w;
            }
        }
    }
    #pragma unroll
    for (int j = 0; j < 4; ++j) {
        const int col = tc * 4 + j;
        #pragma unroll
        for (int i = 0; i < 4; ++i) {
            supT[(size_t)col * N_NODES + n0 + tr * 4 + i] =
                (unsigned short)bfr(acc[i][j]);
        }
    }
}

// Kernel 2: partial[h] = adj[:, h-half] @ support[h-half] (fp32 partials).
// BM=32, BK=64, split-K=2. Grid 512 = 256 row-blocks x 2 K-halves, 512 thr
// (8 waves: wm=w>>2 row-half, wn=w&3 col-quarter; each wave 16x32 out).
// A (adj, HBM stream): global_load_lds into 3x8KB LDS buffers, pre-swizzled
// source, counted vmcnt(1) (2-iter slack), one raw s_barrier per iter.
// B (supT, 2MB L2-resident): direct global->VGPR bf16x8 loads, same-iter use.
#define BK 64
#define KHALF (N_NODES / 2)    // 4096
#define NT (KHALF / BK)        // 64
#define ABUF 8192              // 32 rows x 64 k x fp32

__global__ __launch_bounds__(512) void gcn_kernel(
        const float* __restrict__ adj, const unsigned short* __restrict__ supT,
        float* __restrict__ part) {
    __shared__ char lds[3 * ABUF];
    const int t = threadIdx.x;
    const int l = t & 63;
    const int w = t >> 6;                   // 0..7
    const int r = blockIdx.x & 255;
    const int h = blockIdx.x >> 8;          // K-half
    const int n0 = r * 32;
    const size_t k0 = (size_t)h * KHALF;

    // ---- A staging: wave w stages rows 4w..4w+3; swizzle chunk ^= row&15
    const int s_ar = 4 * w + (l >> 4);
    const char* gA = (const char*)adj
        + ((size_t)(n0 + s_ar) * N_NODES + k0) * 4
        + (((l & 15) ^ (s_ar & 15)) * 16);
    const int adst = w * 1024;              // linear dest: lane*16 within region

    // ---- B direct-load pointers (per-lane): rows f0, f0+16 of supT
    const int wm = w >> 2, wn = w & 3;
    const int f0 = wn * 32 + (l & 15);
    const unsigned short* bp0 = supT + (size_t)f0 * N_NODES + k0 + (l >> 4) * 8;
    const unsigned short* bp1 = bp0 + (size_t)16 * N_NODES;

    // ---- A read offsets
    const int ar = wm * 16 + (l & 15);
    const int a_off = ar * 256;
    const int akey = l & 15;                // == ar & 15
    const int ac0 = (l >> 4) * 2;

    f32x4 acc0 = {0.f, 0.f, 0.f, 0.f};
    f32x4 acc1 = {0.f, 0.f, 0.f, 0.f};

    // prologue: tiles 0,1 -> buffers 0,1 (1 gload/wave each)
    #pragma unroll
    for (int pt = 0; pt < 2; ++pt)
        gload16(gA + (size_t)pt * 256, &lds[pt * ABUF] + adst);

    int bcur = 0;
    for (int tt = 0; tt < NT; ++tt) {
        if (tt < NT - 1) asm volatile("s_waitcnt vmcnt(1)" ::: "memory");
        else             asm volatile("s_waitcnt vmcnt(0)" ::: "memory");
        __builtin_amdgcn_s_barrier();
        asm volatile("" ::: "memory");

        if (tt + 2 < NT) {                  // prefetch tile tt+2 (2-iter slack)
            int b2 = bcur + 2; if (b2 >= 3) b2 -= 3;
            gload16(gA + (size_t)(tt + 2) * 256, &lds[b2 * ABUF] + adst);
        }

        const char* buf = &lds[bcur * ABUF];
        #pragma unroll
        for (int ks = 0; ks < 2; ++ks) {
            const int ca = ks * 8 + ac0;
            f32x4 alo = *(const f32x4*)(buf + a_off + (((ca    ) ^ akey) * 16));
            f32x4 ahi = *(const f32x4*)(buf + a_off + (((ca + 1) ^ akey) * 16));
            bf16x8 b0 = *(const bf16x8*)(bp0 + (size_t)tt * BK + ks * 32);
            bf16x8 b1 = *(const bf16x8*)(bp1 + (size_t)tt * BK + ks * 32);
            bf16x8 af;
            af[0] = bfr(alo.x); af[1] = bfr(alo.y);
            af[2] = bfr(alo.z); af[3] = bfr(alo.w);
            af[4] = bfr(ahi.x); af[5] = bfr(ahi.y);
            af[6] = bfr(ahi.z); af[7] = bfr(ahi.w);
            acc0 = __builtin_amdgcn_mfma_f32_16x16x32_bf16(af, b0, acc0, 0, 0, 0);
            acc1 = __builtin_amdgcn_mfma_f32_16x16x32_bf16(af, b1, acc1, 0, 0, 0);
        }
        ++bcur; if (bcur == 3) bcur = 0;
    }

    // epilogue -> fp32 partial [h][n][f]
    float* p = part + (size_t)h * N_NODES * F_OUT;
    const int col = wn * 32 + (l & 15);
    const int row0 = n0 + wm * 16 + (l >> 4) * 4;
    #pragma unroll
    for (int i = 0; i < 4; ++i) {
        float* o = p + (size_t)(row0 + i) * F_OUT + col;
        o[0]  = acc0[i];
        o[16] = acc1[i];
    }
}

// Kernel 3: out = p0 + p1 + bias
__global__ __launch_bounds__(256) void add_kernel(
        const float* __restrict__ p0, const float* __restrict__ p1,
        const float* __restrict__ bias, float* __restrict__ out) {
    const int i = blockIdx.x * 256 + threadIdx.x;   // 0..131071
    const size_t e = (size_t)i * 8;
    f32x4 a0 = *(const f32x4*)(p0 + e);
    f32x4 a1 = *(const f32x4*)(p0 + e + 4);
    f32x4 c0 = *(const f32x4*)(p1 + e);
    f32x4 c1 = *(const f32x4*)(p1 + e + 4);
    const int fb = (i & 15) * 8;                    // (i*8) % 128
    f32x4 b0 = *(const f32x4*)(bias + fb);
    f32x4 b1 = *(const f32x4*)(bias + fb + 4);
    *(f32x4*)(out + e)     = a0 + c0 + b0;
    *(f32x4*)(out + e + 4) = a1 + c1 + b1;
}

extern "C" void kernel_launch(void* const* d_in, const int* in_sizes, int n_in,
                              void* d_out, int out_size, void* d_ws, size_t ws_size,
                              hipStream_t stream) {
    const float* input  = (const float*)d_in[0];
    const float* adj    = (const float*)d_in[1];
    const float* weight = (const float*)d_in[2];
    const float* bias   = (const float*)d_in[3];
    float* out = (float*)d_out;
    unsigned short* supT = (unsigned short*)d_ws;               // 2 MiB
    float* p0 = (float*)((char*)d_ws + (4u << 20));             // 4 MiB
    float* p1 = (float*)((char*)d_ws + (8u << 20));             // 4 MiB

    support_kernel<<<N_NODES / 32, 256, 0, stream>>>(input, weight, supT);
    gcn_kernel<<<512, 512, 0, stream>>>(adj, supT, p0);         // p0/p1 via h
    add_kernel<<<(N_NODES * F_OUT) / (256 * 8), 256, 0, stream>>>(p0, p1, bias, out);
}

// Round 5
// 112.440 us; speedup vs baseline: 1.3958x; 1.3958x over previous
//
#include <hip/hip_runtime.h>
#include <hip/hip_bf16.h>

#define N_NODES 8192
#define F_IN 256
#define F_OUT 128

#define SPLITK 4
#define KQ (N_NODES / SPLITK)   // 2048
#define BK 64
#define NT (KQ / BK)            // 32
#define ABUF 16384              // 64 rows x 64 k x fp32

typedef __attribute__((ext_vector_type(4))) float f32x4;
typedef __attribute__((ext_vector_type(8))) short bf16x8;
typedef __attribute__((ext_vector_type(4))) unsigned int u32x4;

static __device__ __forceinline__ short bfr(float x) {
    __hip_bfloat16 h = __float2bfloat16(x);   // RNE
    union { __hip_bfloat16 h; short s; } u; u.h = h;
    return u.s;
}

static __device__ __forceinline__ void gload16(const void* g, void* l) {
    __builtin_amdgcn_global_load_lds(
        (const __attribute__((address_space(1))) unsigned int*)g,
        (__attribute__((address_space(3))) unsigned int*)l, 16, 0, 0);
}

// Kernel 1: support^T[f][n] = sum_k X[n][k] * W[k][f]   (fp32 accum -> bf16)
__global__ __launch_bounds__(256) void support_kernel(
        const float* __restrict__ X, const float* __restrict__ W,
        unsigned short* __restrict__ supT) {
    __shared__ float Xs[32][68];
    __shared__ float Ws[64][128];
    const int t = threadIdx.x;
    const int n0 = blockIdx.x * 32;
    const int tc = t & 31;
    const int tr = t >> 5;
    float acc[4][4];
    #pragma unroll
    for (int i = 0; i < 4; ++i)
        #pragma unroll
        for (int j = 0; j < 4; ++j) acc[i][j] = 0.f;

    for (int k0 = 0; k0 < F_IN; k0 += 64) {
        __syncthreads();
        {
            const int r = t >> 3, kc = (t & 7) * 8;
            const float* src = X + (size_t)(n0 + r) * F_IN + k0 + kc;
            f32x4 v0 = *(const f32x4*)src;
            f32x4 v1 = *(const f32x4*)(src + 4);
            *(f32x4*)&Xs[r][kc]     = v0;
            *(f32x4*)&Xs[r][kc + 4] = v1;
        }
        {
            const int col = t & 127, kb = t >> 7;
            #pragma unroll
            for (int i = 0; i < 32; ++i) {
                const int k = kb + i * 2;
                Ws[k][col] = W[(size_t)(k0 + k) * F_OUT + col];
            }
        }
        __syncthreads();
        #pragma unroll 8
        for (int k = 0; k < 64; ++k) {
            const f32x4 b = *(const f32x4*)&Ws[k][tc * 4];
            float a[4];
            #pragma unroll
            for (int i = 0; i < 4; ++i) a[i] = Xs[tr * 4 + i][k];
            #pragma unroll
            for (int i = 0; i < 4; ++i) {
                acc[i][0] += a[i] * b.x; acc[i][1] += a[i] * b.y;
                acc[i][2] += a[i] * b.z; acc[i][3] += a[i] * b.w;
            }
        }
    }
    #pragma unroll
    for (int j = 0; j < 4; ++j) {
        const int col = tc * 4 + j;
        #pragma unroll
        for (int i = 0; i < 4; ++i) {
            supT[(size_t)col * N_NODES + n0 + tr * 4 + i] =
                (unsigned short)bfr(acc[i][j]);
        }
    }
}

// Kernel 2: partial[h] = adj[:, hK] @ support[hK]  (fp32 partials)
// BM=64, BK=64, split-K=4. Grid 512 = 128 rb x 4 h, 512 thr (8 waves 2Mx4N,
// wave = 32x32 out). A: global_load_lds into 4x16KB buffers, swizzled source,
// depth-3 prefetch. B: inline-asm global->VGPR into 4 rotating named sets
// (manual vmcnt ledger: 6 ops/iter -> steady s_waitcnt vmcnt(12)).
__global__ __launch_bounds__(512, 4) void gcn_kernel(
        const float* __restrict__ adj, const unsigned short* __restrict__ supT,
        float* __restrict__ part) {
    __shared__ char lds[4 * ABUF];          // 64 KB
    const int t = threadIdx.x;
    const int l = t & 63;
    const int w = t >> 6;                   // 0..7
    const int rb = blockIdx.x & 127;
    const int h = blockIdx.x >> 7;          // K-quarter
    const int n0 = rb * 64;
    const int k0 = h * KQ;

    // ---- A staging (2 gloads/wave/iter): wave w stages rows 8w..8w+7
    const int r_s0 = 8 * w + (l >> 4);
    const int r_s1 = r_s0 + 4;
    const char* gA0 = (const char*)adj
        + ((size_t)(n0 + r_s0) * N_NODES + k0) * 4
        + (((l & 15) ^ (r_s0 & 15)) * 16);
    const char* gA1 = (const char*)adj
        + ((size_t)(n0 + r_s1) * N_NODES + k0) * 4
        + (((l & 15) ^ (r_s1 & 15)) * 16);
    const int adst0 = w * 2048;
    const int adst1 = adst0 + 1024;

    // ---- B offsets (asm saddr-form: SGPR base = supT, VGPR 32-bit offset)
    const int wm = w >> 2, wn = w & 3;
    const int f0 = wn * 32 + (l & 15);
    unsigned int boff0 = (unsigned)f0 * (N_NODES * 2) + (unsigned)(k0 * 2)
                       + ((l >> 4) * 16);
    unsigned int boff1 = boff0 + 16u * (N_NODES * 2);

    // ---- A read offsets
    const int a_off0 = (wm * 32 + (l & 15)) * 256;
    const int a_off1 = a_off0 + 16 * 256;
    const int akey = l & 15;
    const int ac0 = (l >> 4) * 2;

    f32x4 acc00 = {0.f,0.f,0.f,0.f}, acc01 = {0.f,0.f,0.f,0.f};
    f32x4 acc10 = {0.f,0.f,0.f,0.f}, acc11 = {0.f,0.f,0.f,0.f};

    // 4 rotating named B sets (frags: [n0,ks0],[n0,ks1],[n1,ks0],[n1,ks1])
    u32x4 b0_0, b0_1, b0_2, b0_3;
    u32x4 b1_0, b1_1, b1_2, b1_3;
    u32x4 b2_0, b2_1, b2_2, b2_3;
    u32x4 b3_0, b3_1, b3_2, b3_3;

#define BLD(dst, off, imm) \
    asm volatile("global_load_dwordx4 %0, %1, %2 offset:" imm \
                 : "=v"(dst) : "v"(off), "s"(supT) : "memory")

#define STAGE(W) { \
    BLD(b##W##_0, boff0, "0");  BLD(b##W##_1, boff0, "64"); \
    BLD(b##W##_2, boff1, "0");  BLD(b##W##_3, boff1, "64"); \
    boff0 += 128; boff1 += 128; \
    gload16(gA0, &lds[(W) * ABUF] + adst0); \
    gload16(gA1, &lds[(W) * ABUF] + adst1); \
    gA0 += 256; gA1 += 256; }

#define CVT8(dst, lo, hi) { \
    dst[0] = bfr(lo.x); dst[1] = bfr(lo.y); dst[2] = bfr(lo.z); dst[3] = bfr(lo.w); \
    dst[4] = bfr(hi.x); dst[5] = bfr(hi.y); dst[6] = bfr(hi.z); dst[7] = bfr(hi.w); }

#define BODY(S, W, WAITIMM, DO_STAGE) { \
    asm volatile("s_waitcnt vmcnt(" WAITIMM ")" ::: "memory"); \
    __builtin_amdgcn_sched_barrier(0); \
    __builtin_amdgcn_s_barrier(); \
    asm volatile("" ::: "memory"); \
    if (DO_STAGE) STAGE(W); \
    const char* buf = &lds[(S) * ABUF]; \
    f32x4 m0k0lo = *(const f32x4*)(buf + a_off0 + (((ac0    ) ^ akey) * 16)); \
    f32x4 m0k0hi = *(const f32x4*)(buf + a_off0 + (((ac0 + 1) ^ akey) * 16)); \
    f32x4 m0k1lo = *(const f32x4*)(buf + a_off0 + (((ac0 + 8) ^ akey) * 16)); \
    f32x4 m0k1hi = *(const f32x4*)(buf + a_off0 + (((ac0 + 9) ^ akey) * 16)); \
    f32x4 m1k0lo = *(const f32x4*)(buf + a_off1 + (((ac0    ) ^ akey) * 16)); \
    f32x4 m1k0hi = *(const f32x4*)(buf + a_off1 + (((ac0 + 1) ^ akey) * 16)); \
    f32x4 m1k1lo = *(const f32x4*)(buf + a_off1 + (((ac0 + 8) ^ akey) * 16)); \
    f32x4 m1k1hi = *(const f32x4*)(buf + a_off1 + (((ac0 + 9) ^ akey) * 16)); \
    bf16x8 am0k0, am0k1, am1k0, am1k1; \
    CVT8(am0k0, m0k0lo, m0k0hi); CVT8(am0k1, m0k1lo, m0k1hi); \
    CVT8(am1k0, m1k0lo, m1k0hi); CVT8(am1k1, m1k1lo, m1k1hi); \
    acc00 = __builtin_amdgcn_mfma_f32_16x16x32_bf16(am0k0, __builtin_bit_cast(bf16x8, b##S##_0), acc00, 0, 0, 0); \
    acc01 = __builtin_amdgcn_mfma_f32_16x16x32_bf16(am0k0, __builtin_bit_cast(bf16x8, b##S##_2), acc01, 0, 0, 0); \
    acc10 = __builtin_amdgcn_mfma_f32_16x16x32_bf16(am1k0, __builtin_bit_cast(bf16x8, b##S##_0), acc10, 0, 0, 0); \
    acc11 = __builtin_amdgcn_mfma_f32_16x16x32_bf16(am1k0, __builtin_bit_cast(bf16x8, b##S##_2), acc11, 0, 0, 0); \
    acc00 = __builtin_amdgcn_mfma_f32_16x16x32_bf16(am0k1, __builtin_bit_cast(bf16x8, b##S##_1), acc00, 0, 0, 0); \
    acc01 = __builtin_amdgcn_mfma_f32_16x16x32_bf16(am0k1, __builtin_bit_cast(bf16x8, b##S##_3), acc01, 0, 0, 0); \
    acc10 = __builtin_amdgcn_mfma_f32_16x16x32_bf16(am1k1, __builtin_bit_cast(bf16x8, b##S##_1), acc10, 0, 0, 0); \
    acc11 = __builtin_amdgcn_mfma_f32_16x16x32_bf16(am1k1, __builtin_bit_cast(bf16x8, b##S##_3), acc11, 0, 0, 0); }

    // prologue: tiles 0,1,2 -> sets/buffers 0,1,2 (6 ops each, ledger order)
    STAGE(0); STAGE(1); STAGE(2);

    // main loop: bodies tt = 0..NT-5, uniform vmcnt(12) (keeps iters tt-1,tt-2)
    for (int t4 = 0; t4 < NT - 4; t4 += 4) {
        BODY(0, 3, "12", 1);
        BODY(1, 0, "12", 1);
        BODY(2, 1, "12", 1);
        BODY(3, 2, "12", 1);
    }
    // peeled tail: tt = NT-4..NT-1
    BODY(0, 3, "12", 1);    // tt=28: issues tile 31 (last)
    BODY(1, 0, "12", 0);    // tt=29
    BODY(2, 1, "6",  0);    // tt=30
    BODY(3, 2, "0",  0);    // tt=31

#undef BODY
#undef STAGE
#undef BLD
#undef CVT8

    // epilogue -> fp32 partial [h][n][f]
    float* p = part + (size_t)h * N_NODES * F_OUT;
    const int col = wn * 32 + (l & 15);
    const int row0 = n0 + wm * 32 + (l >> 4) * 4;
    #pragma unroll
    for (int i = 0; i < 4; ++i) {
        float* o0 = p + (size_t)(row0 + i) * F_OUT + col;
        float* o1 = p + (size_t)(row0 + i + 16) * F_OUT + col;
        o0[0]  = acc00[i];
        o0[16] = acc01[i];
        o1[0]  = acc10[i];
        o1[16] = acc11[i];
    }
}

// Kernel 3: out = p0+p1+p2+p3 + bias
__global__ __launch_bounds__(256) void add_kernel(
        const float* __restrict__ part, const float* __restrict__ bias,
        float* __restrict__ out) {
    const int i = blockIdx.x * 256 + threadIdx.x;   // 0..131071
    const size_t e = (size_t)i * 8;
    const size_t ps = (size_t)N_NODES * F_OUT;
    f32x4 s0 = *(const f32x4*)(part + e);
    f32x4 s1 = *(const f32x4*)(part + e + 4);
    #pragma unroll
    for (int h = 1; h < SPLITK; ++h) {
        s0 += *(const f32x4*)(part + h * ps + e);
        s1 += *(const f32x4*)(part + h * ps + e + 4);
    }
    const int fb = (i & 15) * 8;                    // (i*8) % 128
    s0 += *(const f32x4*)(bias + fb);
    s1 += *(const f32x4*)(bias + fb + 4);
    *(f32x4*)(out + e)     = s0;
    *(f32x4*)(out + e + 4) = s1;
}

extern "C" void kernel_launch(void* const* d_in, const int* in_sizes, int n_in,
                              void* d_out, int out_size, void* d_ws, size_t ws_size,
                              hipStream_t stream) {
    const float* input  = (const float*)d_in[0];
    const float* adj    = (const float*)d_in[1];
    const float* weight = (const float*)d_in[2];
    const float* bias   = (const float*)d_in[3];
    float* out = (float*)d_out;
    unsigned short* supT = (unsigned short*)d_ws;           // 2 MiB
    float* part = (float*)((char*)d_ws + (4u << 20));       // 4 x 4 MiB

    support_kernel<<<N_NODES / 32, 256, 0, stream>>>(input, weight, supT);
    gcn_kernel<<<128 * SPLITK, 512, 0, stream>>>(adj, supT, part);
    add_kernel<<<(N_NODES * F_OUT) / (256 * 8), 256, 0, stream>>>(part, bias, out);
}

// Round 6
// 83.657 us; speedup vs baseline: 1.8760x; 1.3441x over previous
//
#include <hip/hip_runtime.h>
#include <hip/hip_bf16.h>

#define N_NODES 8192
#define F_IN 256
#define F_OUT 128

#define SPLITK 4
#define KQ (N_NODES / SPLITK)   // 2048
#define BK 64
#define NT (KQ / BK)            // 32
#define ABYTES 16384            // A tile: 64 rows x 64 k x fp32
#define BBYTES 16384            // B tile: 128 f x 64 k x bf16
#define BUFB (ABYTES + BBYTES)  // 32 KB

typedef __attribute__((ext_vector_type(4))) float f32x4;
typedef __attribute__((ext_vector_type(8))) short bf16x8;

static __device__ __forceinline__ short bfr(float x) {
    __hip_bfloat16 h = __float2bfloat16(x);   // RNE
    union { __hip_bfloat16 h; short s; } u; u.h = h;
    return u.s;
}

static __device__ __forceinline__ void gload16(const void* g, void* l) {
    __builtin_amdgcn_global_load_lds(
        (const __attribute__((address_space(1))) unsigned int*)g,
        (__attribute__((address_space(3))) unsigned int*)l, 16, 0, 0);
}

// Kernel 1: support^T[f][n] = sum_k X[n][k] * W[k][f]   (fp32 accum -> bf16)
__global__ __launch_bounds__(256) void support_kernel(
        const float* __restrict__ X, const float* __restrict__ W,
        unsigned short* __restrict__ supT) {
    __shared__ float Xs[32][68];
    __shared__ float Ws[64][128];
    const int t = threadIdx.x;
    const int n0 = blockIdx.x * 32;
    const int tc = t & 31;
    const int tr = t >> 5;
    float acc[4][4];
    #pragma unroll
    for (int i = 0; i < 4; ++i)
        #pragma unroll
        for (int j = 0; j < 4; ++j) acc[i][j] = 0.f;

    for (int k0 = 0; k0 < F_IN; k0 += 64) {
        __syncthreads();
        {
            const int r = t >> 3, kc = (t & 7) * 8;
            const float* src = X + (size_t)(n0 + r) * F_IN + k0 + kc;
            f32x4 v0 = *(const f32x4*)src;
            f32x4 v1 = *(const f32x4*)(src + 4);
            *(f32x4*)&Xs[r][kc]     = v0;
            *(f32x4*)&Xs[r][kc + 4] = v1;
        }
        {
            const int col = t & 127, kb = t >> 7;
            #pragma unroll
            for (int i = 0; i < 32; ++i) {
                const int k = kb + i * 2;
                Ws[k][col] = W[(size_t)(k0 + k) * F_OUT + col];
            }
        }
        __syncthreads();
        #pragma unroll 8
        for (int k = 0; k < 64; ++k) {
            const f32x4 b = *(const f32x4*)&Ws[k][tc * 4];
            float a[4];
            #pragma unroll
            for (int i = 0; i < 4; ++i) a[i] = Xs[tr * 4 + i][k];
            #pragma unroll
            for (int i = 0; i < 4; ++i) {
                acc[i][0] += a[i] * b.x; acc[i][1] += a[i] * b.y;
                acc[i][2] += a[i] * b.z; acc[i][3] += a[i] * b.w;
            }
        }
    }
    #pragma unroll
    for (int j = 0; j < 4; ++j) {
        const int col = tc * 4 + j;
        #pragma unroll
        for (int i = 0; i < 4; ++i) {
            supT[(size_t)col * N_NODES + n0 + tr * 4 + i] =
                (unsigned short)bfr(acc[i][j]);
        }
    }
}

// Kernel 2: partial[h] = adj[:, hK] @ support[hK]  (fp32 partials)
// BM=64, BK=64, split-K=4. Grid 512 = 128 rb x 4 h, 512 thr (8 waves 2Mx4N,
// wave = 32x32 out). A and B both via global_load_lds into 2x32KB buffers
// (pre-swizzled sources). T3-minimum 2-phase: STAGE(next) -> compute(cur)
// -> vmcnt(0) -> raw s_barrier. Stage-to-wait distance = full compute phase.
__global__ __launch_bounds__(512, 4) void gcn_kernel(
        const float* __restrict__ adj, const unsigned short* __restrict__ supT,
        float* __restrict__ part) {
    __shared__ char lds[2 * BUFB];          // 64 KB
    const int t = threadIdx.x;
    const int l = t & 63;
    const int w = t >> 6;                   // 0..7
    const int rb = blockIdx.x & 127;
    const int h = blockIdx.x >> 7;          // K-quarter
    const int n0 = rb * 64;
    const int k0 = h * KQ;

    // ---- staging sources (per-lane, pre-swizzled) ----
    // A: instr j stages rows 8w+4j .. +3 (l>>4), chunk (l&15)^(row&15)
    const int rA0 = 8 * w + (l >> 4);
    const int rA1 = rA0 + 4;
    const char* gA0 = (const char*)adj
        + ((size_t)(n0 + rA0) * N_NODES + k0) * 4 + (((l & 15) ^ (rA0 & 15)) * 16);
    const char* gA1 = (const char*)adj
        + ((size_t)(n0 + rA1) * N_NODES + k0) * 4 + (((l & 15) ^ (rA1 & 15)) * 16);
    // B: instr j stages f rows 16w+8j+(l>>3), chunk (l&7)^(l>>3)
    const char* gB0 = (const char*)supT
        + ((size_t)(16 * w + (l >> 3)) * N_NODES + k0) * 2 + (((l & 7) ^ (l >> 3)) * 16);
    const char* gB1 = gB0 + (size_t)8 * N_NODES * 2;

    // wave-uniform LDS dest offsets (HW appends lane*16)
    const int a_d0 = w * 2048;
    const int a_d1 = a_d0 + 1024;
    const int b_d0 = ABYTES + w * 2048;
    const int b_d1 = b_d0 + 1024;

    // ---- read-side offsets ----
    const int wm = w >> 2, wn = w & 3;
    const int aoff0 = (wm * 32 + (l & 15)) * 256;   // A row ar0
    const int aoff1 = aoff0 + 16 * 256;             // A row ar0+16
    const int akey = l & 15;
    const int ac0 = (l >> 4) * 2;
    const int boff0 = ABYTES + (wn * 32 + (l & 15)) * 128;
    const int boff1 = boff0 + 16 * 128;
    const int bkey = l & 7;
    const int cb0 = l >> 4;

    f32x4 acc00 = {0.f,0.f,0.f,0.f}, acc01 = {0.f,0.f,0.f,0.f};
    f32x4 acc10 = {0.f,0.f,0.f,0.f}, acc11 = {0.f,0.f,0.f,0.f};

#define STAGE(BUF) { \
    char* bb = &lds[(BUF) * BUFB]; \
    gload16(gA0, bb + a_d0); \
    gload16(gA1, bb + a_d1); \
    gload16(gB0, bb + b_d0); \
    gload16(gB1, bb + b_d1); \
    gA0 += 256; gA1 += 256; gB0 += 128; gB1 += 128; }

#define FENCE_BARRIER() { \
    asm volatile("s_waitcnt vmcnt(0)" ::: "memory"); \
    __builtin_amdgcn_sched_barrier(0); \
    __builtin_amdgcn_s_barrier(); \
    __builtin_amdgcn_sched_barrier(0); }

    // prologue: tile 0 -> buffer 0
    STAGE(0);
    FENCE_BARRIER();

    for (int tt = 0; tt < NT; ++tt) {
        if (tt + 1 < NT) STAGE((tt + 1) & 1);

        const char* buf = &lds[(tt & 1) * BUFB];
        #pragma unroll
        for (int ks = 0; ks < 2; ++ks) {
            const int ca = ks * 8 + ac0;
            f32x4 a0lo = *(const f32x4*)(buf + aoff0 + (((ca    ) ^ akey) * 16));
            f32x4 a0hi = *(const f32x4*)(buf + aoff0 + (((ca + 1) ^ akey) * 16));
            f32x4 a1lo = *(const f32x4*)(buf + aoff1 + (((ca    ) ^ akey) * 16));
            f32x4 a1hi = *(const f32x4*)(buf + aoff1 + (((ca + 1) ^ akey) * 16));
            const int cb = ks * 4 + cb0;
            bf16x8 b0 = *(const bf16x8*)(buf + boff0 + ((cb ^ bkey) * 16));
            bf16x8 b1 = *(const bf16x8*)(buf + boff1 + ((cb ^ bkey) * 16));
            bf16x8 am0, am1;
            am0[0] = bfr(a0lo.x); am0[1] = bfr(a0lo.y);
            am0[2] = bfr(a0lo.z); am0[3] = bfr(a0lo.w);
            am0[4] = bfr(a0hi.x); am0[5] = bfr(a0hi.y);
            am0[6] = bfr(a0hi.z); am0[7] = bfr(a0hi.w);
            am1[0] = bfr(a1lo.x); am1[1] = bfr(a1lo.y);
            am1[2] = bfr(a1lo.z); am1[3] = bfr(a1lo.w);
            am1[4] = bfr(a1hi.x); am1[5] = bfr(a1hi.y);
            am1[6] = bfr(a1hi.z); am1[7] = bfr(a1hi.w);
            acc00 = __builtin_amdgcn_mfma_f32_16x16x32_bf16(am0, b0, acc00, 0, 0, 0);
            acc01 = __builtin_amdgcn_mfma_f32_16x16x32_bf16(am0, b1, acc01, 0, 0, 0);
            acc10 = __builtin_amdgcn_mfma_f32_16x16x32_bf16(am1, b0, acc10, 0, 0, 0);
            acc11 = __builtin_amdgcn_mfma_f32_16x16x32_bf16(am1, b1, acc11, 0, 0, 0);
        }
        FENCE_BARRIER();
    }
#undef STAGE
#undef FENCE_BARRIER

    // epilogue -> fp32 partial [h][n][f]
    float* p = part + (size_t)h * N_NODES * F_OUT;
    const int col = wn * 32 + (l & 15);
    const int row0 = n0 + wm * 32 + (l >> 4) * 4;
    #pragma unroll
    for (int i = 0; i < 4; ++i) {
        float* o0 = p + (size_t)(row0 + i) * F_OUT + col;
        float* o1 = p + (size_t)(row0 + i + 16) * F_OUT + col;
        o0[0]  = acc00[i];
        o0[16] = acc01[i];
        o1[0]  = acc10[i];
        o1[16] = acc11[i];
    }
}

// Kernel 3: out = p0+p1+p2+p3 + bias
__global__ __launch_bounds__(256) void add_kernel(
        const float* __restrict__ part, const float* __restrict__ bias,
        float* __restrict__ out) {
    const int i = blockIdx.x * 256 + threadIdx.x;   // 0..131071
    const size_t e = (size_t)i * 8;
    const size_t ps = (size_t)N_NODES * F_OUT;
    f32x4 s0 = *(const f32x4*)(part + e);
    f32x4 s1 = *(const f32x4*)(part + e + 4);
    #pragma unroll
    for (int h = 1; h < SPLITK; ++h) {
        s0 += *(const f32x4*)(part + h * ps + e);
        s1 += *(const f32x4*)(part + h * ps + e + 4);
    }
    const int fb = (i & 15) * 8;                    // (i*8) % 128
    s0 += *(const f32x4*)(bias + fb);
    s1 += *(const f32x4*)(bias + fb + 4);
    *(f32x4*)(out + e)     = s0;
    *(f32x4*)(out + e + 4) = s1;
}

extern "C" void kernel_launch(void* const* d_in, const int* in_sizes, int n_in,
                              void* d_out, int out_size, void* d_ws, size_t ws_size,
                              hipStream_t stream) {
    const float* input  = (const float*)d_in[0];
    const float* adj    = (const float*)d_in[1];
    const float* weight = (const float*)d_in[2];
    const float* bias   = (const float*)d_in[3];
    float* out = (float*)d_out;
    unsigned short* supT = (unsigned short*)d_ws;           // 2 MiB
    float* part = (float*)((char*)d_ws + (4u << 20));       // 4 x 4 MiB

    support_kernel<<<N_NODES / 32, 256, 0, stream>>>(input, weight, supT);
    gcn_kernel<<<128 * SPLITK, 512, 0, stream>>>(adj, supT, part);
    add_kernel<<<(N_NODES * F_OUT) / (256 * 8), 256, 0, stream>>>(part, bias, out);
}